// Round 8
// baseline (499.587 us; speedup 1.0000x reference)
//
#include <hip/hip_runtime.h>

#define DIN 128      // D_IN == N_HEADS*D_HEAD == 128
#define NHEADS 8
#define DHEAD 16
#define NPB 32       // nodes per block (node_proj)
#define EPB 64       // edges per block (edge mfma kernel)

typedef __attribute__((ext_vector_type(8))) short short8;   // 8 bf16 (4 VGPRs)
typedef __attribute__((ext_vector_type(4))) float f32x4;    // MFMA C/D

__device__ __forceinline__ float clip5(float x) {
    return fminf(fmaxf(x, -5.0f), 5.0f);
}

__device__ __forceinline__ unsigned short f2bf(float f) {   // RNE f32->bf16
    unsigned u = __float_as_uint(f);
    unsigned r = (u + 0x7FFF + ((u >> 16) & 1)) >> 16;
    return (unsigned short)r;
}

__device__ __forceinline__ float b2f(unsigned short u) {    // bf16 -> f32
    return __uint_as_float((unsigned)u << 16);
}

__device__ __forceinline__ float bflo(unsigned u) {  // low bf16 of dword
    return __uint_as_float(u << 16);
}
__device__ __forceinline__ float bfhi(unsigned u) {  // high bf16 of dword
    return __uint_as_float(u & 0xffff0000u);
}

// ---------------- node projections (fp32 VALU, bf16 stores) ----------------

__device__ __forceinline__ void tile_gemm(const float xs[][DIN], int r0, int cg,
                                          const float* __restrict__ W,
                                          float4 acc[4]) {
#pragma unroll 4
    for (int kk = 0; kk < DIN; kk += 4) {
        float4 a[4];
#pragma unroll
        for (int i = 0; i < 4; ++i)
            a[i] = *(const float4*)&xs[r0 + i][kk];
#pragma unroll
        for (int t = 0; t < 4; ++t) {
            float4 w = *(const float4*)&W[(kk + t) * DIN + (cg << 2)];
#pragma unroll
            for (int i = 0; i < 4; ++i) {
                float av = ((const float*)&a[i])[t];
                acc[i].x = fmaf(av, w.x, acc[i].x);
                acc[i].y = fmaf(av, w.y, acc[i].y);
                acc[i].z = fmaf(av, w.z, acc[i].z);
                acc[i].w = fmaf(av, w.w, acc[i].w);
            }
        }
    }
}

__global__ __launch_bounds__(256) void node_proj_kernel(
    const float* __restrict__ x, const float* __restrict__ WQ,
    const float* __restrict__ WK, const float* __restrict__ WV,
    unsigned short* __restrict__ qbf, unsigned short* __restrict__ kbf,
    unsigned short* __restrict__ vbf, int N) {
    __shared__ float xs[NPB][DIN];
    const int tid = threadIdx.x;
    const int n0 = blockIdx.x * NPB;

#pragma unroll
    for (int i = 0; i < NPB * DIN / (256 * 4); ++i) {
        int idx = (tid + i * 256) * 4;
        int r = idx / DIN, c = idx % DIN;
        float4 val = make_float4(0.f, 0.f, 0.f, 0.f);
        if (n0 + r < N) val = *(const float4*)&x[(long)(n0 + r) * DIN + c];
        *(float4*)&xs[r][c] = val;
    }
    __syncthreads();

    const int cg = tid & 31;
    const int ng = tid >> 5;
    const int r0 = ng * 4;

    const float* Ws[3] = {WQ, WK, WV};
    unsigned short* outs[3] = {qbf, kbf, vbf};
#pragma unroll
    for (int m = 0; m < 3; ++m) {
        float4 acc[4] = {make_float4(0,0,0,0), make_float4(0,0,0,0),
                         make_float4(0,0,0,0), make_float4(0,0,0,0)};
        tile_gemm(xs, r0, cg, Ws[m], acc);
#pragma unroll
        for (int i = 0; i < 4; ++i) {
            int n = n0 + r0 + i;
            if (n < N) {
                ushort4 b;
                b.x = f2bf(acc[i].x); b.y = f2bf(acc[i].y);
                b.z = f2bf(acc[i].z); b.w = f2bf(acc[i].w);
                *(ushort4*)&outs[m][(long)n * DIN + (cg << 2)] = b;
            }
        }
    }
}

// ---------------- CSR build (counting sort by destination col) ----------------

__global__ __launch_bounds__(256) void degree_kernel(
    const int* __restrict__ cols, int* __restrict__ deg, int E) {
    int e = blockIdx.x * 256 + threadIdx.x;
    if (e < E) atomicAdd(&deg[cols[e]], 1);
}

__global__ __launch_bounds__(256) void block_sum_kernel(
    const int* __restrict__ deg, int* __restrict__ bsum, int N) {
    __shared__ int s[256];
    int tid = threadIdx.x;
    int i = blockIdx.x * 256 + tid;
    s[tid] = (i < N) ? deg[i] : 0;
    __syncthreads();
    for (int st = 128; st > 0; st >>= 1) {
        if (tid < st) s[tid] += s[tid + st];
        __syncthreads();
    }
    if (tid == 0) bsum[blockIdx.x] = s[0];
}

__global__ __launch_bounds__(256) void scan_bsum_kernel(int* __restrict__ bsum, int NB) {
    __shared__ int s[256];
    int tid = threadIdx.x;
    int v = (tid < NB) ? bsum[tid] : 0;
    s[tid] = v;
    __syncthreads();
    for (int off = 1; off < 256; off <<= 1) {
        int t = (tid >= off) ? s[tid - off] : 0;
        __syncthreads();
        s[tid] += t;
        __syncthreads();
    }
    if (tid < NB) bsum[tid] = s[tid] - v;   // exclusive
}

__global__ __launch_bounds__(256) void offsets_kernel(
    const int* __restrict__ deg, const int* __restrict__ bsumscan,
    int* __restrict__ offsets, int* __restrict__ cursor, int N, int E) {
    __shared__ int s[256];
    int tid = threadIdx.x;
    int i = blockIdx.x * 256 + tid;
    int v = (i < N) ? deg[i] : 0;
    s[tid] = v;
    __syncthreads();
    for (int off = 1; off < 256; off <<= 1) {
        int t = (tid >= off) ? s[tid - off] : 0;
        __syncthreads();
        s[tid] += t;
        __syncthreads();
    }
    int excl = s[tid] - v + bsumscan[blockIdx.x];
    if (i < N) { offsets[i] = excl; cursor[i] = excl; }
    if (blockIdx.x == 0 && tid == 0) offsets[N] = E;
}

__global__ __launch_bounds__(256) void scatter_kernel(
    const int* __restrict__ cols, int* __restrict__ cursor,
    int* __restrict__ elist, int E) {
    int e = blockIdx.x * 256 + threadIdx.x;
    if (e >= E) return;
    int pos = atomicAdd(&cursor[cols[e]], 1);
    elist[pos] = e;
}

// ---------------- WE -> bf16 transposed [n][k] ----------------

__global__ __launch_bounds__(256) void prep_wet_kernel(
    const float* __restrict__ WE, unsigned short* __restrict__ WEt) {
    int idx = blockIdx.x * 256 + threadIdx.x;    // 16384 total
    int kk = idx >> 7, n = idx & 127;
    WEt[n * DIN + kk] = f2bf(WE[kk * DIN + n]);
}

// ---------------- edge compute: MFMA e_proj + e_out + ax ----------------
// 256 threads = 4 waves, 64 edges/block. A = WEt features (M), B = edges (N)
// -> lane holds edge = lane&15, features lg*4+i (contiguous). k/q are bf16:
// 16 hoisted ushort4 gathers = 32 VGPRs total -> the full burst survives
// regalloc (R6/R7: float4 version got re-sunk, VGPR stuck at 48-56).

__global__ __launch_bounds__(256) void edge_mfma_kernel(
    const float* __restrict__ edge_attr, const int* __restrict__ edge_index,
    const unsigned short* __restrict__ WEt, const unsigned short* __restrict__ qbf,
    const unsigned short* __restrict__ kbf, float* __restrict__ e_out,
    float* __restrict__ ax, int E) {
    __shared__ unsigned short As[EPB * DIN];      // 16 KB, XOR-swizzled
    __shared__ int rows_s[EPB], cols_s[EPB];
    const int tid = threadIdx.x;
    const int e0 = blockIdx.x * EPB;              // E % EPB == 0

    if (tid < EPB) {
        rows_s[tid] = edge_index[e0 + tid];
        cols_s[tid] = edge_index[E + e0 + tid];
    }
    // stage edge_attr -> bf16 LDS (swizzle: 16B slot ^= row&7)
#pragma unroll
    for (int i = 0; i < EPB * DIN / (256 * 4); ++i) {    // 8 iters
        int idx = (tid + i * 256) * 4;
        int r = idx >> 7, c = idx & 127;
        float4 val = *(const float4*)&edge_attr[(long)(e0 + r) * DIN + c];
        ushort4 b;
        b.x = f2bf(val.x); b.y = f2bf(val.y); b.z = f2bf(val.z); b.w = f2bf(val.w);
        int byte = (r * 256 + c * 2) ^ ((r & 7) << 4);
        *(ushort4*)((char*)As + byte) = b;
    }
    __syncthreads();

    const int w = tid >> 6;          // wave 0..3: edges w*16..w*16+15
    const int l = tid & 63;
    const int lr = l & 15;
    const int lg = l >> 4;
    const int el = w * 16 + lr;      // this lane's edge within block
    const int er = rows_s[el], ec = cols_s[el];
    const long eg = e0 + el;         // global edge id

    // ---- hoisted gathers: 16 independent 8B loads, fenced in place ----
    const unsigned short* krow = &kbf[(long)er * DIN + lg * 4];
    const unsigned short* qrow = &qbf[(long)ec * DIN + lg * 4];
    ushort4 kv[8], qv[8];
#pragma unroll
    for (int ft = 0; ft < 8; ++ft) {
        kv[ft] = *(const ushort4*)&krow[ft * 16];
        qv[ft] = *(const ushort4*)&qrow[ft * 16];
    }
    __builtin_amdgcn_sched_barrier(0);   // loads stay a burst

    // B fragments (edge rows) from swizzled LDS: k-window = ks*32 + lg*8
    short8 bfrag[4];
#pragma unroll
    for (int ks = 0; ks < 4; ++ks) {
        int byte = (el * 256 + ks * 64 + lg * 16) ^ ((el & 7) << 4);
        bfrag[ks] = *(const short8*)((const char*)As + byte);
    }

#pragma unroll
    for (int ft = 0; ft < 8; ++ft) {             // ft == head
        f32x4 acc = (f32x4){0.f, 0.f, 0.f, 0.f};
#pragma unroll
        for (int ks = 0; ks < 4; ++ks) {
            short8 af = *(const short8*)&WEt[(ft * 16 + lr) * DIN + ks * 32 + lg * 8];
            acc = __builtin_amdgcn_mfma_f32_16x16x32_bf16(af, bfrag[ks], acc, 0, 0, 0);
        }
        const int f0 = ft * 16 + lg * 4;         // 4 consecutive features
        float4 t;
        t.x = clip5(b2f(kv[ft].x) * b2f(qv[ft].x) * 0.25f) * acc[0];
        t.y = clip5(b2f(kv[ft].y) * b2f(qv[ft].y) * 0.25f) * acc[1];
        t.z = clip5(b2f(kv[ft].z) * b2f(qv[ft].z) * 0.25f) * acc[2];
        t.w = clip5(b2f(kv[ft].w) * b2f(qv[ft].w) * 0.25f) * acc[3];
        *(float4*)&e_out[eg * DIN + f0] = t;

        float s = t.x + t.y + t.z + t.w;         // this lane's 4-feature partial
        s += __shfl_xor(s, 16);                  // reduce over lg groups
        s += __shfl_xor(s, 32);
        float axv = expf(clip5(s));
        if (lg == 0)
            ax[eg * NHEADS + ft] = axv;
    }
}

// ---------------- per-node gather aggregation (no atomics) ----------------
// batch-8 over a node's edges: 8 independent ax + 8 bf16 v-row gathers in
// flight. Loads are unconditional (clamped index), masked by a=0.

__global__ __launch_bounds__(256) void aggregate_kernel(
    const int* __restrict__ offsets, const int* __restrict__ elist,
    const int* __restrict__ rows, const float* __restrict__ ax,
    const unsigned short* __restrict__ vbf, float* __restrict__ h_out, int N) {
    int wid = blockIdx.x * 4 + (threadIdx.x >> 6);   // one wave per node
    int lane = threadIdx.x & 63;
    if (wid >= N) return;
    int beg = offsets[wid], end = offsets[wid + 1];
    const int head = lane >> 3;

    float2 acc = make_float2(0.f, 0.f);
    float zacc = 0.f;

    for (int j = beg; j < end; j += 8) {
        int n = end - j; n = (n > 8) ? 8 : n;
        int e_[8], r_[8];
#pragma unroll
        for (int t = 0; t < 8; ++t)
            e_[t] = elist[j + ((t < n) ? t : 0)];
#pragma unroll
        for (int t = 0; t < 8; ++t)
            r_[t] = rows[e_[t]];
        float a_[8]; unsigned u_[8];
#pragma unroll
        for (int t = 0; t < 8; ++t) {
            a_[t] = (t < n) ? ax[(long)e_[t] * NHEADS + head] : 0.f;
            u_[t] = *(const unsigned*)&vbf[(long)r_[t] * DIN + lane * 2];
        }
#pragma unroll
        for (int t = 0; t < 8; ++t) {
            acc.x = fmaf(bflo(u_[t]), a_[t], acc.x);
            acc.y = fmaf(bfhi(u_[t]), a_[t], acc.y);
            zacc += a_[t];
        }
    }
    float inv = 1.0f / (zacc + 1e-6f);
    float2 res = make_float2(acc.x * inv, acc.y * inv);
    *(float2*)&h_out[(long)wid * DIN + lane * 2] = res;
}

extern "C" void kernel_launch(void* const* d_in, const int* in_sizes, int n_in,
                              void* d_out, int out_size, void* d_ws, size_t ws_size,
                              hipStream_t stream) {
    const float* x         = (const float*)d_in[0];
    const float* edge_attr = (const float*)d_in[1];
    const int*   edge_index= (const int*)d_in[2];
    const float* WQ        = (const float*)d_in[3];
    const float* WK        = (const float*)d_in[4];
    const float* WV        = (const float*)d_in[5];
    const float* WE        = (const float*)d_in[6];

    const int N = in_sizes[0] / DIN;     // 50000
    const int E = in_sizes[2] / 2;       // 600000 (multiple of 64)
    const int NB = (N + 255) / 256;

    float* out   = (float*)d_out;
    float* h_out = out;                        // [N,128]
    float* e_out = out + (long)N * DIN;        // [E,128]

    unsigned short* qbf = (unsigned short*)d_ws;            // [N,128] bf16
    unsigned short* kbf = qbf + (long)N * DIN;              // [N,128] bf16
    unsigned short* vbf = kbf + (long)N * DIN;              // [N,128] bf16
    float* ax = (float*)(vbf + (long)N * DIN);              // [E,8]
    unsigned short* WEt = (unsigned short*)(ax + (long)E * NHEADS);  // [128,128] bf16
    int* ip      = (int*)(WEt + DIN * DIN);
    int* deg     = ip;                         // [N]
    int* cursor  = deg + N;                    // [N]
    int* offsets = cursor + N;                 // [N+1]
    int* bsum    = offsets + N + 1;            // [NB]
    int* elist   = bsum + 256;                 // [E]

    const int* rows = edge_index;
    const int* cols = edge_index + E;

    hipMemsetAsync(deg, 0, (size_t)N * sizeof(int), stream);

    node_proj_kernel<<<(N + NPB - 1) / NPB, 256, 0, stream>>>(x, WQ, WK, WV, qbf, kbf, vbf, N);
    prep_wet_kernel<<<DIN * DIN / 256, 256, 0, stream>>>(WE, WEt);

    degree_kernel<<<(E + 255) / 256, 256, 0, stream>>>(cols, deg, E);
    block_sum_kernel<<<NB, 256, 0, stream>>>(deg, bsum, N);
    scan_bsum_kernel<<<1, 256, 0, stream>>>(bsum, NB);
    offsets_kernel<<<NB, 256, 0, stream>>>(deg, bsum, offsets, cursor, N, E);
    scatter_kernel<<<(E + 255) / 256, 256, 0, stream>>>(cols, cursor, elist, E);

    edge_mfma_kernel<<<E / EPB, 256, 0, stream>>>(
        edge_attr, edge_index, WEt, qbf, kbf, e_out, ax, E);

    aggregate_kernel<<<(N + 3) / 4, 256, 0, stream>>>(
        offsets, elist, rows, ax, vbf, h_out, N);
}

// Round 9
// 494.714 us; speedup vs baseline: 1.0098x; 1.0098x over previous
//
#include <hip/hip_runtime.h>

#define DIN 128      // D_IN == N_HEADS*D_HEAD == 128
#define NHEADS 8
#define DHEAD 16
#define NPB 32       // nodes per block (node_proj)
#define EPB 64       // edges per block (edge mfma kernel)

typedef __attribute__((ext_vector_type(8))) short short8;   // 8 bf16 (4 VGPRs)
typedef __attribute__((ext_vector_type(4))) float f32x4;    // MFMA C/D

__device__ __forceinline__ float clip5(float x) {
    return fminf(fmaxf(x, -5.0f), 5.0f);
}

__device__ __forceinline__ unsigned short f2bf(float f) {   // RNE f32->bf16
    unsigned u = __float_as_uint(f);
    unsigned r = (u + 0x7FFF + ((u >> 16) & 1)) >> 16;
    return (unsigned short)r;
}

__device__ __forceinline__ float b2f(unsigned short u) {    // bf16 -> f32
    return __uint_as_float((unsigned)u << 16);
}

__device__ __forceinline__ float bflo(unsigned u) {  // low bf16 of dword
    return __uint_as_float(u << 16);
}
__device__ __forceinline__ float bfhi(unsigned u) {  // high bf16 of dword
    return __uint_as_float(u & 0xffff0000u);
}

// ---------------- node projections (fp32 VALU, bf16 stores) ----------------

__device__ __forceinline__ void tile_gemm(const float xs[][DIN], int r0, int cg,
                                          const float* __restrict__ W,
                                          float4 acc[4]) {
#pragma unroll 4
    for (int kk = 0; kk < DIN; kk += 4) {
        float4 a[4];
#pragma unroll
        for (int i = 0; i < 4; ++i)
            a[i] = *(const float4*)&xs[r0 + i][kk];
#pragma unroll
        for (int t = 0; t < 4; ++t) {
            float4 w = *(const float4*)&W[(kk + t) * DIN + (cg << 2)];
#pragma unroll
            for (int i = 0; i < 4; ++i) {
                float av = ((const float*)&a[i])[t];
                acc[i].x = fmaf(av, w.x, acc[i].x);
                acc[i].y = fmaf(av, w.y, acc[i].y);
                acc[i].z = fmaf(av, w.z, acc[i].z);
                acc[i].w = fmaf(av, w.w, acc[i].w);
            }
        }
    }
}

__global__ __launch_bounds__(256) void node_proj_kernel(
    const float* __restrict__ x, const float* __restrict__ WQ,
    const float* __restrict__ WK, const float* __restrict__ WV,
    unsigned short* __restrict__ qbf, unsigned short* __restrict__ kbf,
    unsigned short* __restrict__ vbf, int N) {
    __shared__ float xs[NPB][DIN];
    const int tid = threadIdx.x;
    const int n0 = blockIdx.x * NPB;

#pragma unroll
    for (int i = 0; i < NPB * DIN / (256 * 4); ++i) {
        int idx = (tid + i * 256) * 4;
        int r = idx / DIN, c = idx % DIN;
        float4 val = make_float4(0.f, 0.f, 0.f, 0.f);
        if (n0 + r < N) val = *(const float4*)&x[(long)(n0 + r) * DIN + c];
        *(float4*)&xs[r][c] = val;
    }
    __syncthreads();

    const int cg = tid & 31;
    const int ng = tid >> 5;
    const int r0 = ng * 4;

    const float* Ws[3] = {WQ, WK, WV};
    unsigned short* outs[3] = {qbf, kbf, vbf};
#pragma unroll
    for (int m = 0; m < 3; ++m) {
        float4 acc[4] = {make_float4(0,0,0,0), make_float4(0,0,0,0),
                         make_float4(0,0,0,0), make_float4(0,0,0,0)};
        tile_gemm(xs, r0, cg, Ws[m], acc);
#pragma unroll
        for (int i = 0; i < 4; ++i) {
            int n = n0 + r0 + i;
            if (n < N) {
                ushort4 b;
                b.x = f2bf(acc[i].x); b.y = f2bf(acc[i].y);
                b.z = f2bf(acc[i].z); b.w = f2bf(acc[i].w);
                *(ushort4*)&outs[m][(long)n * DIN + (cg << 2)] = b;
            }
        }
    }
}

// ---------------- CSR build (counting sort by destination col) ----------------

__global__ __launch_bounds__(256) void degree_kernel(
    const int* __restrict__ cols, int* __restrict__ deg, int E) {
    int e = blockIdx.x * 256 + threadIdx.x;
    if (e < E) atomicAdd(&deg[cols[e]], 1);
}

__global__ __launch_bounds__(256) void block_sum_kernel(
    const int* __restrict__ deg, int* __restrict__ bsum, int N) {
    __shared__ int s[256];
    int tid = threadIdx.x;
    int i = blockIdx.x * 256 + tid;
    s[tid] = (i < N) ? deg[i] : 0;
    __syncthreads();
    for (int st = 128; st > 0; st >>= 1) {
        if (tid < st) s[tid] += s[tid + st];
        __syncthreads();
    }
    if (tid == 0) bsum[blockIdx.x] = s[0];
}

__global__ __launch_bounds__(256) void scan_bsum_kernel(int* __restrict__ bsum, int NB) {
    __shared__ int s[256];
    int tid = threadIdx.x;
    int v = (tid < NB) ? bsum[tid] : 0;
    s[tid] = v;
    __syncthreads();
    for (int off = 1; off < 256; off <<= 1) {
        int t = (tid >= off) ? s[tid - off] : 0;
        __syncthreads();
        s[tid] += t;
        __syncthreads();
    }
    if (tid < NB) bsum[tid] = s[tid] - v;   // exclusive
}

__global__ __launch_bounds__(256) void offsets_kernel(
    const int* __restrict__ deg, const int* __restrict__ bsumscan,
    int* __restrict__ offsets, int* __restrict__ cursor, int N, int E) {
    __shared__ int s[256];
    int tid = threadIdx.x;
    int i = blockIdx.x * 256 + tid;
    int v = (i < N) ? deg[i] : 0;
    s[tid] = v;
    __syncthreads();
    for (int off = 1; off < 256; off <<= 1) {
        int t = (tid >= off) ? s[tid - off] : 0;
        __syncthreads();
        s[tid] += t;
        __syncthreads();
    }
    int excl = s[tid] - v + bsumscan[blockIdx.x];
    if (i < N) { offsets[i] = excl; cursor[i] = excl; }
    if (blockIdx.x == 0 && tid == 0) offsets[N] = E;
}

__global__ __launch_bounds__(256) void scatter_kernel(
    const int* __restrict__ cols, int* __restrict__ cursor,
    int* __restrict__ elist, int E) {
    int e = blockIdx.x * 256 + threadIdx.x;
    if (e >= E) return;
    int pos = atomicAdd(&cursor[cols[e]], 1);
    elist[pos] = e;
}

// ---------------- WE -> bf16 transposed [n][k] ----------------

__global__ __launch_bounds__(256) void prep_wet_kernel(
    const float* __restrict__ WE, unsigned short* __restrict__ WEt) {
    int idx = blockIdx.x * 256 + threadIdx.x;    // 16384 total
    int kk = idx >> 7, n = idx & 127;
    WEt[n * DIN + kk] = f2bf(WE[kk * DIN + n]);
}

// ---------------- edge compute: MFMA e_proj + e_out + ax ----------------
// 256 threads = 4 waves, 64 edges/block, NO LDS / NO barrier: edge_attr has
// zero intra-block reuse, so each lane loads its own B-fragment source
// (32B contiguous per ks, coalesced across the wave: 16 consecutive rows
// x 4 lanes) directly from global, converts to bf16 in registers while the
// 16 k/q gathers are in flight. 24 outstanding vmem ops per lane.

__global__ __launch_bounds__(256) void edge_mfma_kernel(
    const float* __restrict__ edge_attr, const int* __restrict__ edge_index,
    const unsigned short* __restrict__ WEt, const unsigned short* __restrict__ qbf,
    const unsigned short* __restrict__ kbf, float* __restrict__ e_out,
    float* __restrict__ ax, int E) {
    const int tid = threadIdx.x;
    const int e0 = blockIdx.x * EPB;              // E % EPB == 0
    const int w = tid >> 6;          // wave 0..3: edges w*16..w*16+15
    const int l = tid & 63;
    const int lr = l & 15;
    const int lg = l >> 4;
    const int el = w * 16 + lr;      // this lane's edge within block
    const long eg = e0 + el;         // global edge id
    const int er = edge_index[eg];
    const int ec = edge_index[E + eg];

    // ---- burst 1: 8 edge_attr float4 loads (own row, coalesced) ----
    const float* arow = &edge_attr[eg * DIN + lg * 8];
    float4 ea[8];
#pragma unroll
    for (int ks = 0; ks < 4; ++ks) {
        ea[ks * 2]     = *(const float4*)&arow[ks * 32];
        ea[ks * 2 + 1] = *(const float4*)&arow[ks * 32 + 4];
    }
    // ---- burst 2: 16 k/q ushort4 gathers (issued after ea -> consuming
    // ea below waits only vmcnt(16), conversions overlap gather latency) ----
    const unsigned short* krow = &kbf[(long)er * DIN + lg * 4];
    const unsigned short* qrow = &qbf[(long)ec * DIN + lg * 4];
    ushort4 kv[8], qv[8];
#pragma unroll
    for (int ft = 0; ft < 8; ++ft) {
        kv[ft] = *(const ushort4*)&krow[ft * 16];
        qv[ft] = *(const ushort4*)&qrow[ft * 16];
    }
    __builtin_amdgcn_sched_barrier(0);   // loads stay a burst

    // convert edge_attr -> bf16 B-fragments (k-window = ks*32 + lg*8)
    short8 bfrag[4];
#pragma unroll
    for (int ks = 0; ks < 4; ++ks) {
        float4 a0 = ea[ks * 2], a1 = ea[ks * 2 + 1];
        short8 f;
        f[0] = (short)f2bf(a0.x); f[1] = (short)f2bf(a0.y);
        f[2] = (short)f2bf(a0.z); f[3] = (short)f2bf(a0.w);
        f[4] = (short)f2bf(a1.x); f[5] = (short)f2bf(a1.y);
        f[6] = (short)f2bf(a1.z); f[7] = (short)f2bf(a1.w);
        bfrag[ks] = f;
    }

#pragma unroll
    for (int ft = 0; ft < 8; ++ft) {             // ft == head
        f32x4 acc = (f32x4){0.f, 0.f, 0.f, 0.f};
#pragma unroll
        for (int ks = 0; ks < 4; ++ks) {
            short8 af = *(const short8*)&WEt[(ft * 16 + lr) * DIN + ks * 32 + lg * 8];
            acc = __builtin_amdgcn_mfma_f32_16x16x32_bf16(af, bfrag[ks], acc, 0, 0, 0);
        }
        const int f0 = ft * 16 + lg * 4;         // 4 consecutive features
        float4 t;
        t.x = clip5(b2f(kv[ft].x) * b2f(qv[ft].x) * 0.25f) * acc[0];
        t.y = clip5(b2f(kv[ft].y) * b2f(qv[ft].y) * 0.25f) * acc[1];
        t.z = clip5(b2f(kv[ft].z) * b2f(qv[ft].z) * 0.25f) * acc[2];
        t.w = clip5(b2f(kv[ft].w) * b2f(qv[ft].w) * 0.25f) * acc[3];
        *(float4*)&e_out[eg * DIN + f0] = t;

        float s = t.x + t.y + t.z + t.w;         // this lane's 4-feature partial
        s += __shfl_xor(s, 16);                  // reduce over lg groups
        s += __shfl_xor(s, 32);
        float axv = __expf(clip5(s));
        if (lg == 0)
            ax[eg * NHEADS + ft] = axv;
    }
}

// ---------------- per-node gather aggregation (no atomics) ----------------
// batch-8 over a node's edges: 8 independent ax + 8 bf16 v-row gathers in
// flight. Loads are unconditional (clamped index), masked by a=0.

__global__ __launch_bounds__(256) void aggregate_kernel(
    const int* __restrict__ offsets, const int* __restrict__ elist,
    const int* __restrict__ rows, const float* __restrict__ ax,
    const unsigned short* __restrict__ vbf, float* __restrict__ h_out, int N) {
    int wid = blockIdx.x * 4 + (threadIdx.x >> 6);   // one wave per node
    int lane = threadIdx.x & 63;
    if (wid >= N) return;
    int beg = offsets[wid], end = offsets[wid + 1];
    const int head = lane >> 3;

    float2 acc = make_float2(0.f, 0.f);
    float zacc = 0.f;

    for (int j = beg; j < end; j += 8) {
        int n = end - j; n = (n > 8) ? 8 : n;
        int e_[8], r_[8];
#pragma unroll
        for (int t = 0; t < 8; ++t)
            e_[t] = elist[j + ((t < n) ? t : 0)];
#pragma unroll
        for (int t = 0; t < 8; ++t)
            r_[t] = rows[e_[t]];
        float a_[8]; unsigned u_[8];
#pragma unroll
        for (int t = 0; t < 8; ++t) {
            a_[t] = (t < n) ? ax[(long)e_[t] * NHEADS + head] : 0.f;
            u_[t] = *(const unsigned*)&vbf[(long)r_[t] * DIN + lane * 2];
        }
#pragma unroll
        for (int t = 0; t < 8; ++t) {
            acc.x = fmaf(bflo(u_[t]), a_[t], acc.x);
            acc.y = fmaf(bfhi(u_[t]), a_[t], acc.y);
            zacc += a_[t];
        }
    }
    float inv = 1.0f / (zacc + 1e-6f);
    float2 res = make_float2(acc.x * inv, acc.y * inv);
    *(float2*)&h_out[(long)wid * DIN + lane * 2] = res;
}

extern "C" void kernel_launch(void* const* d_in, const int* in_sizes, int n_in,
                              void* d_out, int out_size, void* d_ws, size_t ws_size,
                              hipStream_t stream) {
    const float* x         = (const float*)d_in[0];
    const float* edge_attr = (const float*)d_in[1];
    const int*   edge_index= (const int*)d_in[2];
    const float* WQ        = (const float*)d_in[3];
    const float* WK        = (const float*)d_in[4];
    const float* WV        = (const float*)d_in[5];
    const float* WE        = (const float*)d_in[6];

    const int N = in_sizes[0] / DIN;     // 50000
    const int E = in_sizes[2] / 2;       // 600000 (multiple of 64)
    const int NB = (N + 255) / 256;

    float* out   = (float*)d_out;
    float* h_out = out;                        // [N,128]
    float* e_out = out + (long)N * DIN;        // [E,128]

    unsigned short* qbf = (unsigned short*)d_ws;            // [N,128] bf16
    unsigned short* kbf = qbf + (long)N * DIN;              // [N,128] bf16
    unsigned short* vbf = kbf + (long)N * DIN;              // [N,128] bf16
    float* ax = (float*)(vbf + (long)N * DIN);              // [E,8]
    unsigned short* WEt = (unsigned short*)(ax + (long)E * NHEADS);  // [128,128] bf16
    int* ip      = (int*)(WEt + DIN * DIN);
    int* deg     = ip;                         // [N]
    int* cursor  = deg + N;                    // [N]
    int* offsets = cursor + N;                 // [N+1]
    int* bsum    = offsets + N + 1;            // [NB]
    int* elist   = bsum + 256;                 // [E]

    const int* rows = edge_index;
    const int* cols = edge_index + E;

    hipMemsetAsync(deg, 0, (size_t)N * sizeof(int), stream);

    node_proj_kernel<<<(N + NPB - 1) / NPB, 256, 0, stream>>>(x, WQ, WK, WV, qbf, kbf, vbf, N);
    prep_wet_kernel<<<DIN * DIN / 256, 256, 0, stream>>>(WE, WEt);

    degree_kernel<<<(E + 255) / 256, 256, 0, stream>>>(cols, deg, E);
    block_sum_kernel<<<NB, 256, 0, stream>>>(deg, bsum, N);
    scan_bsum_kernel<<<1, 256, 0, stream>>>(bsum, NB);
    offsets_kernel<<<NB, 256, 0, stream>>>(deg, bsum, offsets, cursor, N, E);
    scatter_kernel<<<(E + 255) / 256, 256, 0, stream>>>(cols, cursor, elist, E);

    edge_mfma_kernel<<<E / EPB, 256, 0, stream>>>(
        edge_attr, edge_index, WEt, qbf, kbf, e_out, ax, E);

    aggregate_kernel<<<(N + 3) / 4, 256, 0, stream>>>(
        offsets, elist, rows, ax, vbf, h_out, N);
}

// Round 13
// 485.669 us; speedup vs baseline: 1.0287x; 1.0186x over previous
//
#include <hip/hip_runtime.h>

#define DIN 128      // D_IN == N_HEADS*D_HEAD == 128
#define NHEADS 8
#define DHEAD 16
#define NPB 32       // nodes per block (node_proj)
#define EPB 64       // edges per block (edge mfma kernel)

typedef __attribute__((ext_vector_type(8))) short short8;   // 8 bf16 (4 VGPRs)
typedef __attribute__((ext_vector_type(4))) float f32x4;    // MFMA C/D + NT ld/st

__device__ __forceinline__ float clip5(float x) {
    return fminf(fmaxf(x, -5.0f), 5.0f);
}

__device__ __forceinline__ unsigned short f2bf(float f) {   // RNE f32->bf16
    unsigned u = __float_as_uint(f);
    unsigned r = (u + 0x7FFF + ((u >> 16) & 1)) >> 16;
    return (unsigned short)r;
}

__device__ __forceinline__ float b2f(unsigned short u) {    // bf16 -> f32
    return __uint_as_float((unsigned)u << 16);
}

__device__ __forceinline__ float bflo(unsigned u) {  // low bf16 of dword
    return __uint_as_float(u << 16);
}
__device__ __forceinline__ float bfhi(unsigned u) {  // high bf16 of dword
    return __uint_as_float(u & 0xffff0000u);
}

// ---------------- node projections (fp32 VALU, bf16 stores) ----------------

__device__ __forceinline__ void tile_gemm(const float xs[][DIN], int r0, int cg,
                                          const float* __restrict__ W,
                                          float4 acc[4]) {
#pragma unroll 4
    for (int kk = 0; kk < DIN; kk += 4) {
        float4 a[4];
#pragma unroll
        for (int i = 0; i < 4; ++i)
            a[i] = *(const float4*)&xs[r0 + i][kk];
#pragma unroll
        for (int t = 0; t < 4; ++t) {
            float4 w = *(const float4*)&W[(kk + t) * DIN + (cg << 2)];
#pragma unroll
            for (int i = 0; i < 4; ++i) {
                float av = ((const float*)&a[i])[t];
                acc[i].x = fmaf(av, w.x, acc[i].x);
                acc[i].y = fmaf(av, w.y, acc[i].y);
                acc[i].z = fmaf(av, w.z, acc[i].z);
                acc[i].w = fmaf(av, w.w, acc[i].w);
            }
        }
    }
}

__global__ __launch_bounds__(256) void node_proj_kernel(
    const float* __restrict__ x, const float* __restrict__ WQ,
    const float* __restrict__ WK, const float* __restrict__ WV,
    unsigned short* __restrict__ qbf, unsigned short* __restrict__ kbf,
    unsigned short* __restrict__ vbf, int N) {
    __shared__ float xs[NPB][DIN];
    const int tid = threadIdx.x;
    const int n0 = blockIdx.x * NPB;

#pragma unroll
    for (int i = 0; i < NPB * DIN / (256 * 4); ++i) {
        int idx = (tid + i * 256) * 4;
        int r = idx / DIN, c = idx % DIN;
        float4 val = make_float4(0.f, 0.f, 0.f, 0.f);
        if (n0 + r < N) val = *(const float4*)&x[(long)(n0 + r) * DIN + c];
        *(float4*)&xs[r][c] = val;
    }
    __syncthreads();

    const int cg = tid & 31;
    const int ng = tid >> 5;
    const int r0 = ng * 4;

    const float* Ws[3] = {WQ, WK, WV};
    unsigned short* outs[3] = {qbf, kbf, vbf};
#pragma unroll
    for (int m = 0; m < 3; ++m) {
        float4 acc[4] = {make_float4(0,0,0,0), make_float4(0,0,0,0),
                         make_float4(0,0,0,0), make_float4(0,0,0,0)};
        tile_gemm(xs, r0, cg, Ws[m], acc);
#pragma unroll
        for (int i = 0; i < 4; ++i) {
            int n = n0 + r0 + i;
            if (n < N) {
                ushort4 b;
                b.x = f2bf(acc[i].x); b.y = f2bf(acc[i].y);
                b.z = f2bf(acc[i].z); b.w = f2bf(acc[i].w);
                *(ushort4*)&outs[m][(long)n * DIN + (cg << 2)] = b;
            }
        }
    }
}

// ---------------- CSR build (counting sort by destination col) ----------------

__global__ __launch_bounds__(256) void degree_kernel(
    const int* __restrict__ cols, int* __restrict__ deg, int E) {
    int e = blockIdx.x * 256 + threadIdx.x;
    if (e < E) atomicAdd(&deg[cols[e]], 1);
}

__global__ __launch_bounds__(256) void block_sum_kernel(
    const int* __restrict__ deg, int* __restrict__ bsum, int N) {
    __shared__ int s[256];
    int tid = threadIdx.x;
    int i = blockIdx.x * 256 + tid;
    s[tid] = (i < N) ? deg[i] : 0;
    __syncthreads();
    for (int st = 128; st > 0; st >>= 1) {
        if (tid < st) s[tid] += s[tid + st];
        __syncthreads();
    }
    if (tid == 0) bsum[blockIdx.x] = s[0];
}

__global__ __launch_bounds__(256) void scan_bsum_kernel(int* __restrict__ bsum, int NB) {
    __shared__ int s[256];
    int tid = threadIdx.x;
    int v = (tid < NB) ? bsum[tid] : 0;
    s[tid] = v;
    __syncthreads();
    for (int off = 1; off < 256; off <<= 1) {
        int t = (tid >= off) ? s[tid - off] : 0;
        __syncthreads();
        s[tid] += t;
        __syncthreads();
    }
    if (tid < NB) bsum[tid] = s[tid] - v;   // exclusive
}

__global__ __launch_bounds__(256) void offsets_kernel(
    const int* __restrict__ deg, const int* __restrict__ bsumscan,
    int* __restrict__ offsets, int* __restrict__ cursor, int N, int E) {
    __shared__ int s[256];
    int tid = threadIdx.x;
    int i = blockIdx.x * 256 + tid;
    int v = (i < N) ? deg[i] : 0;
    s[tid] = v;
    __syncthreads();
    for (int off = 1; off < 256; off <<= 1) {
        int t = (tid >= off) ? s[tid - off] : 0;
        __syncthreads();
        s[tid] += t;
        __syncthreads();
    }
    int excl = s[tid] - v + bsumscan[blockIdx.x];
    if (i < N) { offsets[i] = excl; cursor[i] = excl; }
    if (blockIdx.x == 0 && tid == 0) offsets[N] = E;
}

// scatter also materializes sorted endpoint arrays: rows_s/cols_s[j] for
// j in elist order -> downstream kernels read them contiguously.
__global__ __launch_bounds__(256) void scatter_kernel(
    const int* __restrict__ rows, const int* __restrict__ cols,
    int* __restrict__ cursor, int* __restrict__ elist,
    int* __restrict__ rows_s, int* __restrict__ cols_s, int E) {
    int e = blockIdx.x * 256 + threadIdx.x;
    if (e >= E) return;
    int c = cols[e];
    int pos = atomicAdd(&cursor[c], 1);
    elist[pos] = e;
    rows_s[pos] = rows[e];
    cols_s[pos] = c;
}

// ---------------- WE -> bf16 transposed [n][k] ----------------

__global__ __launch_bounds__(256) void prep_wet_kernel(
    const float* __restrict__ WE, unsigned short* __restrict__ WEt) {
    int idx = blockIdx.x * 256 + threadIdx.x;    // 16384 total
    int kk = idx >> 7, n = idx & 127;
    WEt[n * DIN + kk] = f2bf(WE[kk * DIN + n]);
}

// ---------------- edge compute: MFMA e_proj + e_out + ax_s ----------------
// Processes edges in elist (destination-sorted) order: consecutive lanes
// share ec -> q gathers collapse to a few L1-hot lines per wave. ax written
// contiguously at sorted position j for the aggregate kernel. e_out / ea
// are nontemporal (touched exactly once) so q/k/v stay cache-resident.

__global__ __launch_bounds__(256) void edge_mfma_kernel(
    const float* __restrict__ edge_attr, const int* __restrict__ elist,
    const int* __restrict__ rows_s, const int* __restrict__ cols_s,
    const unsigned short* __restrict__ WEt, const unsigned short* __restrict__ qbf,
    const unsigned short* __restrict__ kbf, float* __restrict__ e_out,
    float* __restrict__ ax_s, int E) {
    const int tid = threadIdx.x;
    const int e0 = blockIdx.x * EPB;              // E % EPB == 0
    const int w = tid >> 6;          // wave 0..3: sorted slots w*16..w*16+15
    const int l = tid & 63;
    const int lr = l & 15;
    const int lg = l >> 4;
    const int j = e0 + w * 16 + lr;  // sorted position
    const long eg = elist[j];        // original edge id (row gather target)
    const int er = rows_s[j];        // contiguous
    const int ec = cols_s[j];        // contiguous, sorted (locality!)

    // ---- burst 1: 8 edge_attr f32x4 loads (own row, nontemporal) ----
    const float* arow = &edge_attr[eg * DIN + lg * 8];
    f32x4 ea[8];
#pragma unroll
    for (int ks = 0; ks < 4; ++ks) {
        ea[ks * 2]     = __builtin_nontemporal_load((const f32x4*)&arow[ks * 32]);
        ea[ks * 2 + 1] = __builtin_nontemporal_load((const f32x4*)&arow[ks * 32 + 4]);
    }
    // ---- burst 2: 16 k/q ushort4 gathers ----
    const unsigned short* krow = &kbf[(long)er * DIN + lg * 4];
    const unsigned short* qrow = &qbf[(long)ec * DIN + lg * 4];
    ushort4 kv[8], qv[8];
#pragma unroll
    for (int ft = 0; ft < 8; ++ft) {
        kv[ft] = *(const ushort4*)&krow[ft * 16];
        qv[ft] = *(const ushort4*)&qrow[ft * 16];
    }
    __builtin_amdgcn_sched_barrier(0);   // loads stay a burst

    // convert edge_attr -> bf16 B-fragments (k-window = ks*32 + lg*8)
    short8 bfrag[4];
#pragma unroll
    for (int ks = 0; ks < 4; ++ks) {
        f32x4 a0 = ea[ks * 2], a1 = ea[ks * 2 + 1];
        short8 f;
        f[0] = (short)f2bf(a0[0]); f[1] = (short)f2bf(a0[1]);
        f[2] = (short)f2bf(a0[2]); f[3] = (short)f2bf(a0[3]);
        f[4] = (short)f2bf(a1[0]); f[5] = (short)f2bf(a1[1]);
        f[6] = (short)f2bf(a1[2]); f[7] = (short)f2bf(a1[3]);
        bfrag[ks] = f;
    }

#pragma unroll
    for (int ft = 0; ft < 8; ++ft) {             // ft == head
        f32x4 acc = (f32x4){0.f, 0.f, 0.f, 0.f};
#pragma unroll
        for (int ks = 0; ks < 4; ++ks) {
            short8 af = *(const short8*)&WEt[(ft * 16 + lr) * DIN + ks * 32 + lg * 8];
            acc = __builtin_amdgcn_mfma_f32_16x16x32_bf16(af, bfrag[ks], acc, 0, 0, 0);
        }
        const int f0 = ft * 16 + lg * 4;         // 4 consecutive features
        f32x4 t;
        t[0] = clip5(b2f(kv[ft].x) * b2f(qv[ft].x) * 0.25f) * acc[0];
        t[1] = clip5(b2f(kv[ft].y) * b2f(qv[ft].y) * 0.25f) * acc[1];
        t[2] = clip5(b2f(kv[ft].z) * b2f(qv[ft].z) * 0.25f) * acc[2];
        t[3] = clip5(b2f(kv[ft].w) * b2f(qv[ft].w) * 0.25f) * acc[3];
        __builtin_nontemporal_store(t, (f32x4*)&e_out[eg * DIN + f0]);

        float s = t[0] + t[1] + t[2] + t[3];     // this lane's 4-feature partial
        s += __shfl_xor(s, 16);                  // reduce over lg groups
        s += __shfl_xor(s, 32);
        float axv = __expf(clip5(s));
        if (lg == 0)
            ax_s[(long)j * NHEADS + ft] = axv;   // contiguous in sorted order
    }
}

// ---------------- per-node gather aggregation (no atomics) ----------------
// ax_s and rows_s are contiguous per node (sorted); only v is a gather.
// batch-8: 8 independent v-row gathers in flight.

__global__ __launch_bounds__(256) void aggregate_kernel(
    const int* __restrict__ offsets, const int* __restrict__ rows_s,
    const float* __restrict__ ax_s, const unsigned short* __restrict__ vbf,
    float* __restrict__ h_out, int N) {
    int wid = blockIdx.x * 4 + (threadIdx.x >> 6);   // one wave per node
    int lane = threadIdx.x & 63;
    if (wid >= N) return;
    int beg = offsets[wid], end = offsets[wid + 1];
    const int head = lane >> 3;

    float2 acc = make_float2(0.f, 0.f);
    float zacc = 0.f;

    for (int j = beg; j < end; j += 8) {
        int n = end - j; n = (n > 8) ? 8 : n;
        int r_[8]; float a_[8]; unsigned u_[8];
#pragma unroll
        for (int t = 0; t < 8; ++t)
            r_[t] = rows_s[j + ((t < n) ? t : 0)];        // contiguous
#pragma unroll
        for (int t = 0; t < 8; ++t) {
            a_[t] = (t < n) ? ax_s[(long)(j + t) * NHEADS + head] : 0.f;  // contiguous
            u_[t] = *(const unsigned*)&vbf[(long)r_[t] * DIN + lane * 2]; // gather
        }
#pragma unroll
        for (int t = 0; t < 8; ++t) {
            acc.x = fmaf(bflo(u_[t]), a_[t], acc.x);
            acc.y = fmaf(bfhi(u_[t]), a_[t], acc.y);
            zacc += a_[t];
        }
    }
    float inv = 1.0f / (zacc + 1e-6f);
    float2 res = make_float2(acc.x * inv, acc.y * inv);
    *(float2*)&h_out[(long)wid * DIN + lane * 2] = res;
}

extern "C" void kernel_launch(void* const* d_in, const int* in_sizes, int n_in,
                              void* d_out, int out_size, void* d_ws, size_t ws_size,
                              hipStream_t stream) {
    const float* x         = (const float*)d_in[0];
    const float* edge_attr = (const float*)d_in[1];
    const int*   edge_index= (const int*)d_in[2];
    const float* WQ        = (const float*)d_in[3];
    const float* WK        = (const float*)d_in[4];
    const float* WV        = (const float*)d_in[5];
    const float* WE        = (const float*)d_in[6];

    const int N = in_sizes[0] / DIN;     // 50000
    const int E = in_sizes[2] / 2;       // 600000 (multiple of 64)
    const int NB = (N + 255) / 256;

    float* out   = (float*)d_out;
    float* h_out = out;                        // [N,128]
    float* e_out = out + (long)N * DIN;        // [E,128]

    unsigned short* qbf = (unsigned short*)d_ws;            // [N,128] bf16
    unsigned short* kbf = qbf + (long)N * DIN;              // [N,128] bf16
    unsigned short* vbf = kbf + (long)N * DIN;              // [N,128] bf16
    float* ax_s = (float*)(vbf + (long)N * DIN);            // [E,8] sorted order
    unsigned short* WEt = (unsigned short*)(ax_s + (long)E * NHEADS);  // [128,128] bf16
    int* ip      = (int*)(WEt + DIN * DIN);
    int* deg     = ip;                         // [N]
    int* cursor  = deg + N;                    // [N]
    int* offsets = cursor + N;                 // [N+1]
    int* bsum    = offsets + N + 1;            // [NB]
    int* elist   = bsum + 256;                 // [E]
    int* rows_s  = elist + E;                  // [E]
    int* cols_s  = rows_s + E;                 // [E]

    const int* rows = edge_index;
    const int* cols = edge_index + E;

    hipMemsetAsync(deg, 0, (size_t)N * sizeof(int), stream);

    node_proj_kernel<<<(N + NPB - 1) / NPB, 256, 0, stream>>>(x, WQ, WK, WV, qbf, kbf, vbf, N);
    prep_wet_kernel<<<DIN * DIN / 256, 256, 0, stream>>>(WE, WEt);

    degree_kernel<<<(E + 255) / 256, 256, 0, stream>>>(cols, deg, E);
    block_sum_kernel<<<NB, 256, 0, stream>>>(deg, bsum, N);
    scan_bsum_kernel<<<1, 256, 0, stream>>>(bsum, NB);
    offsets_kernel<<<NB, 256, 0, stream>>>(deg, bsum, offsets, cursor, N, E);
    scatter_kernel<<<(E + 255) / 256, 256, 0, stream>>>(rows, cols, cursor,
                                                        elist, rows_s, cols_s, E);

    edge_mfma_kernel<<<E / EPB, 256, 0, stream>>>(
        edge_attr, elist, rows_s, cols_s, WEt, qbf, kbf, e_out, ax_s, E);

    aggregate_kernel<<<(N + 3) / 4, 256, 0, stream>>>(
        offsets, rows_s, ax_s, vbf, h_out, N);
}